// Round 5
// baseline (231.947 us; speedup 1.0000x reference)
//
#include <hip/hip_runtime.h>

// ValleFlashAttention on MI355X (gfx950).
// B=2, N=2048, C=1024, H=16, hd=64. PAD_TAIL=128 (keys >= 1920 masked).
// causal_start read from d_in[2].
//
// Round 5:
//  - Attention rewritten: waves split the K axis (16-key slices), Q in regs,
//    K/V read directly from global (L2) — NO barriers / NO LDS in the hot loop.
//    No-max softmax (exp2 direct; masked -> -1e30 -> 0): P goes register-direct
//    from the S^T MFMA D-layout into the PV B-operand (tile-paired 16x16x32).
//    Per-part cross-wave O/l reduction through 49 KB LDS (2 barriers/part).
//  - q pre-scale folds hd^-0.5 * log2(e).
//  - proj GEMM: 128x64 tiles, grid 512 (2 blocks/CU).
//  - cvt: single fused launch.

typedef unsigned short ushort_t;
typedef short short4v __attribute__((ext_vector_type(4)));
typedef short short8 __attribute__((ext_vector_type(8)));
typedef float floatx4 __attribute__((ext_vector_type(4)));
typedef unsigned short ushort4v __attribute__((ext_vector_type(4)));

#define MFMA16(a, b, c) __builtin_amdgcn_mfma_f32_16x16x32_bf16(a, b, c, 0, 0, 0)

__device__ __forceinline__ ushort_t f2bf(float f) {   // RNE
  unsigned int u = __float_as_uint(f);
  u += 0x7fffu + ((u >> 16) & 1u);
  return (ushort_t)(u >> 16);
}
__device__ __forceinline__ ushort_t f2bf_ru(float f) {  // round-half-up, 2 ops
  return (ushort_t)((__float_as_uint(f) + 0x8000u) >> 16);
}

__device__ __forceinline__ void gl_lds16(const ushort_t* g, ushort_t* l) {
  __builtin_amdgcn_global_load_lds(
      (const __attribute__((address_space(1))) void*)g,
      (__attribute__((address_space(3))) void*)l, 16, 0, 0);
}

// ---------------------------------------------------------------- fused cvt
// x: 4194304 elems, w_qkv: 3145728, w_proj: 1048576 (boundaries all %4==0)
__global__ __launch_bounds__(256) void cvt3_kernel(
    const float* __restrict__ x, const float* __restrict__ wq,
    const float* __restrict__ wp, ushort_t* __restrict__ xb,
    ushort_t* __restrict__ wqb, ushort_t* __restrict__ wpb) {
  size_t i = ((size_t)blockIdx.x * 256 + threadIdx.x) * 4;
  const float* s;
  ushort_t* d;
  size_t off;
  if (i < 4194304) { s = x; d = xb; off = i; }
  else if (i < 7340032) { s = wq; d = wqb; off = i - 4194304; }
  else { s = wp; d = wpb; off = i - 7340032; }
  float4 v = *(const float4*)(s + off);
  ushort4v o;
  o.x = f2bf(v.x); o.y = f2bf(v.y); o.z = f2bf(v.z); o.w = f2bf(v.w);
  *(ushort4v*)(d + off) = o;
}

// ---------------------------------------------------------------- QKV GEMM
// C[m][n] = sum_k A[m][k]*Bm[n][k]. 128x128 tile, BK=32, m97 staging.
// q scale folds hd^-0.5 * log2e = 0.125 * 1.44269504.
__global__ __launch_bounds__(256) void gemm_qkv(
    const ushort_t* __restrict__ A, const ushort_t* __restrict__ Bm,
    float* __restrict__ present, ushort_t* __restrict__ q_ws,
    ushort_t* __restrict__ k_ws, ushort_t* __restrict__ vT_ws) {
  const int K = 1024, TN = 24;
  __shared__ __align__(16) ushort_t As[128 * 32];
  __shared__ __align__(16) ushort_t Bs[128 * 32];
  const int tid = threadIdx.x;
  const int wave = tid >> 6, lane = tid & 63;
  const int quad = lane >> 4, l16 = lane & 15;
  const int wm = wave >> 1, wn = wave & 1;
  const int tm = blockIdx.x / TN, tn = blockIdx.x % TN;

  const int r0 = tid >> 2, c0 = (tid & 3) * 8;
  const int r1 = r0 + 64;
  const ushort_t* a0 = A + (size_t)(tm * 128 + r0) * K + c0;
  const ushort_t* a1 = A + (size_t)(tm * 128 + r1) * K + c0;
  const ushort_t* b0 = Bm + (size_t)(tn * 128 + r0) * K + c0;
  const ushort_t* b1 = Bm + (size_t)(tn * 128 + r1) * K + c0;
  ushort_t* lA0 = As + tid * 8;
  ushort_t* lA1 = As + (tid + 256) * 8;
  ushort_t* lB0 = Bs + tid * 8;
  ushort_t* lB1 = Bs + (tid + 256) * 8;

  floatx4 acc[4][4] = {};

  for (int k0 = 0; k0 < K; k0 += 32) {
    __syncthreads();
    gl_lds16(a0 + k0, lA0);
    gl_lds16(a1 + k0, lA1);
    gl_lds16(b0 + k0, lB0);
    gl_lds16(b1 + k0, lB1);
    __syncthreads();
    short8 af[4], bfr[4];
#pragma unroll
    for (int mi = 0; mi < 4; ++mi)
      af[mi] = *(const short8*)(As + (wm * 64 + mi * 16 + l16) * 32 + quad * 8);
#pragma unroll
    for (int ni = 0; ni < 4; ++ni)
      bfr[ni] = *(const short8*)(Bs + (wn * 64 + ni * 16 + l16) * 32 + quad * 8);
#pragma unroll
    for (int mi = 0; mi < 4; ++mi)
#pragma unroll
      for (int ni = 0; ni < 4; ++ni)
        acc[mi][ni] = MFMA16(af[mi], bfr[ni], acc[mi][ni]);
  }

#pragma unroll
  for (int mi = 0; mi < 4; ++mi) {
#pragma unroll
    for (int ni = 0; ni < 4; ++ni) {
      const int gm0 = tm * 128 + wm * 64 + mi * 16 + quad * 4;
      const int gn = tn * 128 + wn * 64 + ni * 16 + l16;
      const int b = gm0 >> 11, pos0 = gm0 & 2047;
      const int which = gn >> 10, rem = gn & 1023;
      const int h = rem >> 6, d = rem & 63;
      const size_t hb = (size_t)(b * 16 + h);
      if (which == 0) {
#pragma unroll
        for (int r = 0; r < 4; ++r)
          q_ws[(hb * 2048 + pos0 + r) * 64 + d] =
              f2bf(acc[mi][ni][r] * 0.18033688f);  // 0.125 * log2(e)
      } else if (which == 1) {
#pragma unroll
        for (int r = 0; r < 4; ++r) {
          size_t pk = (hb * 2048 + pos0 + r) * 64 + d;
          present[pk] = acc[mi][ni][r];
          k_ws[pk] = f2bf(acc[mi][ni][r]);
        }
      } else {
#pragma unroll
        for (int r = 0; r < 4; ++r)
          present[((size_t)((2 + b) * 16 + h) * 2048 + pos0 + r) * 64 + d] =
              acc[mi][ni][r];
        ushort4v pk4;
        pk4.x = f2bf(acc[mi][ni][0]); pk4.y = f2bf(acc[mi][ni][1]);
        pk4.z = f2bf(acc[mi][ni][2]); pk4.w = f2bf(acc[mi][ni][3]);
        *(ushort4v*)(vT_ws + (hb * 64 + d) * 2048 + pos0) = pk4;
      }
    }
  }
}

// ---------------------------------------------------------------- proj GEMM
// 128x64 tiles, grid 32*16=512 (2 blocks/CU). out = A @ W^T + bias.
__global__ __launch_bounds__(256) void gemm_proj(
    const ushort_t* __restrict__ A, const ushort_t* __restrict__ Bm,
    float* __restrict__ outf, const float* __restrict__ b_proj) {
  const int K = 1024;
  __shared__ __align__(16) ushort_t As[128 * 32];
  __shared__ __align__(16) ushort_t Bs[64 * 32];
  const int tid = threadIdx.x;
  const int wave = tid >> 6, lane = tid & 63;
  const int quad = lane >> 4, l16 = lane & 15;
  const int wm = wave >> 1, wn = wave & 1;
  const int tm = blockIdx.x >> 4, tn = blockIdx.x & 15;

  const int r0 = tid >> 2, c0 = (tid & 3) * 8;
  const int r1 = r0 + 64;
  const int rB = tid >> 2;  // 64 rows, 1 chunk/thread
  const ushort_t* a0 = A + (size_t)(tm * 128 + r0) * K + c0;
  const ushort_t* a1 = A + (size_t)(tm * 128 + r1) * K + c0;
  const ushort_t* bg = Bm + (size_t)(tn * 64 + rB) * K + c0;
  ushort_t* lA0 = As + tid * 8;
  ushort_t* lA1 = As + (tid + 256) * 8;
  ushort_t* lB = Bs + tid * 8;

  floatx4 acc[4][2] = {};

  for (int k0 = 0; k0 < K; k0 += 32) {
    __syncthreads();
    gl_lds16(a0 + k0, lA0);
    gl_lds16(a1 + k0, lA1);
    gl_lds16(bg + k0, lB);
    __syncthreads();
    short8 af[4], bfr[2];
#pragma unroll
    for (int mi = 0; mi < 4; ++mi)
      af[mi] = *(const short8*)(As + (wm * 64 + mi * 16 + l16) * 32 + quad * 8);
#pragma unroll
    for (int ni = 0; ni < 2; ++ni)
      bfr[ni] = *(const short8*)(Bs + (wn * 32 + ni * 16 + l16) * 32 + quad * 8);
#pragma unroll
    for (int mi = 0; mi < 4; ++mi)
#pragma unroll
      for (int ni = 0; ni < 2; ++ni)
        acc[mi][ni] = MFMA16(af[mi], bfr[ni], acc[mi][ni]);
  }

#pragma unroll
  for (int mi = 0; mi < 4; ++mi)
#pragma unroll
    for (int ni = 0; ni < 2; ++ni) {
      const int gm0 = tm * 128 + wm * 64 + mi * 16 + quad * 4;
      const int gn = tn * 64 + wn * 32 + ni * 16 + l16;
#pragma unroll
      for (int r = 0; r < 4; ++r)
        outf[(size_t)(gm0 + r) * 1024 + gn] = acc[mi][ni][r] + b_proj[gn];
    }
}

// ---------------------------------------------------------------- flash attention
// grid 512: gid -> (bh = gid&31, qp = gid>>5); block does q-tiles (qp, 31-qp).
// Wave w owns the 16-key slice [kt0+16w, kt0+16w+16) of each 64-key tile;
// Q (64 rows) lives in registers. No barriers / no LDS in the hot loop.
// S^T = K_slice Q^T (D rows = keys); exp2 direct (no max-sub); P goes
// register-direct into the PV B-operand via tile-pairing (16x16x32).
// Per-part cross-wave O/l reduction through LDS.
__global__ __launch_bounds__(256, 2) void attn_kernel(
    const ushort_t* __restrict__ qw, const ushort_t* __restrict__ kw,
    const ushort_t* __restrict__ vtw, ushort_t* __restrict__ attn_out,
    const int* __restrict__ cs_ptr) {
  // Os[dc][j][qc]: partials for d-chunk dc from the 3 waves j != dc (48 KB).
  __shared__ __align__(16) float Os[4 * 3 * 4 * 256];
  __shared__ float Ls[4 * 64];  // [wave][qc*16+l16]
  const int tid = threadIdx.x;
  const int wave = tid >> 6, lane = tid & 63;
  const int quad = lane >> 4, l16 = lane & 15;
  const int gid = blockIdx.x;
  const int bh = gid & 31, qp = gid >> 5;
  const int b = bh >> 4, h = bh & 15;
  const int cs = cs_ptr[0];
  const size_t headP = (size_t)bh * 2048 * 64;

  // wave-slice base pointers (advance by tile)
  const ushort_t* kbase = kw + headP + (size_t)(16 * wave + l16) * 64 + quad * 8;
  const ushort_t* vbase = vtw + headP + (size_t)l16 * 2048 + 16 * wave + quad * 4;

  for (int part = 0; part < 2; ++part) {
    const int qt = part ? (31 - qp) : qp;
    const int q0 = qt * 64;

    // Q as B-operand frags: B[n=q=l16][k=d=hh*32+quad*8+j]
    short8 qf[4][2];
#pragma unroll
    for (int qc = 0; qc < 4; ++qc)
#pragma unroll
      for (int hh = 0; hh < 2; ++hh)
        qf[qc][hh] = *(const short8*)(qw + headP +
            (size_t)(q0 + qc * 16 + l16) * 64 + hh * 32 + quad * 8);

    floatx4 OT[4][4] = {};   // [dc][qc]; lane: d=dc*16+quad*4+r, q=qc*16+l16
    float lq[4] = {0.f, 0.f, 0.f, 0.f};

    const int nt = (min(1920, max(q0 + 64, cs)) + 63) >> 6;
    const int lastk = max(q0 + 63, cs - 1);
    int ntw = ((lastk - 16 * wave) >> 6) + 1;   // monotone-allowed tiles for slice
    if (ntw > nt) ntw = nt;

    for (int tp = 0; tp < ntw; tp += 2) {
      const bool has_o = (tp + 1 < ntw);
      const int k0e = tp * 64 + 16 * wave;
      const int k0o = k0e + 64;

      // loads (odd tile loads always in-bounds; contribution zeroed via pb_o)
      const short8 kae0 = *(const short8*)(kbase + (size_t)tp * 4096);
      const short8 kae1 = *(const short8*)(kbase + (size_t)tp * 4096 + 32);
      const short8 kao0 = *(const short8*)(kbase + (size_t)(tp + 1) * 4096);
      const short8 kao1 = *(const short8*)(kbase + (size_t)(tp + 1) * 4096 + 32);
      short4v vae[4], vao[4];
#pragma unroll
      for (int dc = 0; dc < 4; ++dc) {
        vae[dc] = *(const short4v*)(vbase + dc * 32768 + (size_t)tp * 64);
        vao[dc] = *(const short4v*)(vbase + dc * 32768 + (size_t)(tp + 1) * 64);
      }

      short4v pbe[4], pbo[4];
      // ---- even tile
      {
        floatx4 ST[4];
#pragma unroll
        for (int qc = 0; qc < 4; ++qc) {
          floatx4 z = {0.f, 0.f, 0.f, 0.f};
          z = MFMA16(kae0, qf[qc][0], z);
          ST[qc] = MFMA16(kae1, qf[qc][1], z);
        }
        if (k0e + 15 > q0 && k0e + 15 >= cs) {
#pragma unroll
          for (int qc = 0; qc < 4; ++qc)
#pragma unroll
            for (int r = 0; r < 4; ++r) {
              int k = k0e + quad * 4 + r, q = q0 + qc * 16 + l16;
              if (!(k <= q || k < cs)) ST[qc][r] = -1e30f;
            }
        }
#pragma unroll
        for (int qc = 0; qc < 4; ++qc) {
          float p0 = exp2f(ST[qc][0]), p1 = exp2f(ST[qc][1]);
          float p2 = exp2f(ST[qc][2]), p3 = exp2f(ST[qc][3]);
          lq[qc] += (p0 + p1) + (p2 + p3);
          short4v pb;
          pb.x = (short)f2bf_ru(p0); pb.y = (short)f2bf_ru(p1);
          pb.z = (short)f2bf_ru(p2); pb.w = (short)f2bf_ru(p3);
          pbe[qc] = pb;
        }
      }
      // ---- odd tile
      if (has_o) {
        floatx4 ST[4];
#pragma unroll
        for (int qc = 0; qc < 4; ++qc) {
          floatx4 z = {0.f, 0.f, 0.f, 0.f};
          z = MFMA16(kao0, qf[qc][0], z);
          ST[qc] = MFMA16(kao1, qf[qc][1], z);
        }
        if (k0o + 15 > q0 && k0o + 15 >= cs) {
#pragma unroll
          for (int qc = 0; qc < 4; ++qc)
#pragma unroll
            for (int r = 0; r < 4; ++r) {
              int k = k0o + quad * 4 + r, q = q0 + qc * 16 + l16;
              if (!(k <= q || k < cs)) ST[qc][r] = -1e30f;
            }
        }
#pragma unroll
        for (int qc = 0; qc < 4; ++qc) {
          float p0 = exp2f(ST[qc][0]), p1 = exp2f(ST[qc][1]);
          float p2 = exp2f(ST[qc][2]), p3 = exp2f(ST[qc][3]);
          lq[qc] += (p0 + p1) + (p2 + p3);
          short4v pb;
          pb.x = (short)f2bf_ru(p0); pb.y = (short)f2bf_ru(p1);
          pb.z = (short)f2bf_ru(p2); pb.w = (short)f2bf_ru(p3);
          pbo[qc] = pb;
        }
      } else {
#pragma unroll
        for (int qc = 0; qc < 4; ++qc) {
          short4v zz = {0, 0, 0, 0};
          pbo[qc] = zz;
        }
      }

      // ---- paired PV: A = concat(V_e, V_o), B = concat(P_e, P_o), K=32
      short8 pb8[4];
#pragma unroll
      for (int qc = 0; qc < 4; ++qc)
        pb8[qc] = __builtin_shufflevector(pbe[qc], pbo[qc], 0, 1, 2, 3, 4, 5, 6, 7);
#pragma unroll
      for (int dc = 0; dc < 4; ++dc) {
        short8 va8 = __builtin_shufflevector(vae[dc], vao[dc], 0, 1, 2, 3, 4, 5, 6, 7);
#pragma unroll
        for (int qc = 0; qc < 4; ++qc)
          OT[dc][qc] = MFMA16(va8, pb8[qc], OT[dc][qc]);
      }
    }

    // ---- cross-wave reduction (only LDS + barriers in the kernel)
#pragma unroll
    for (int qc = 0; qc < 4; ++qc) {
      lq[qc] += __shfl_xor(lq[qc], 16, 64);
      lq[qc] += __shfl_xor(lq[qc], 32, 64);
    }
    if (quad == 0) {
#pragma unroll
      for (int qc = 0; qc < 4; ++qc) Ls[wave * 64 + qc * 16 + l16] = lq[qc];
    }
#pragma unroll
    for (int dc = 0; dc < 4; ++dc) {
      if (dc == wave) continue;  // keep own d-chunk in registers
      const int j = (wave < dc) ? wave : wave - 1;
#pragma unroll
      for (int qc = 0; qc < 4; ++qc)
        *(floatx4*)(Os + ((dc * 3 + j) * 4 + qc) * 256 + lane * 4) = OT[dc][qc];
    }
    __syncthreads();

    // wave w finalizes d-chunk w for all q
#pragma unroll
    for (int qc = 0; qc < 4; ++qc) {
      floatx4 acc = OT[wave][qc];
#pragma unroll
      for (int j = 0; j < 3; ++j)
        acc += *(const floatx4*)(Os + ((wave * 3 + j) * 4 + qc) * 256 + lane * 4);
      float lt = Ls[qc * 16 + l16] + Ls[64 + qc * 16 + l16] +
                 Ls[128 + qc * 16 + l16] + Ls[192 + qc * 16 + l16];
      const float inv = 1.f / lt;
      ushort4v o4;
      o4.x = f2bf(acc[0] * inv); o4.y = f2bf(acc[1] * inv);
      o4.z = f2bf(acc[2] * inv); o4.w = f2bf(acc[3] * inv);
      *(ushort4v*)(attn_out + (size_t)(b * 2048 + q0 + qc * 16 + l16) * 1024 +
                   h * 64 + wave * 16 + quad * 4) = o4;
    }
    __syncthreads();  // scratch safe to reuse in next part
  }
}

// ---------------------------------------------------------------- launch
extern "C" void kernel_launch(void* const* d_in, const int* in_sizes, int n_in,
                              void* d_out, int out_size, void* d_ws, size_t ws_size,
                              hipStream_t stream) {
  const float* x      = (const float*)d_in[0];
  const int*   cs     = (const int*)d_in[2];
  const float* w_qkv  = (const float*)d_in[3];
  const float* w_proj = (const float*)d_in[4];
  const float* b_proj = (const float*)d_in[5];

  float* out     = (float*)d_out;
  float* present = out + (size_t)2 * 2048 * 1024;

  char* ws = (char*)d_ws;
  ushort_t* xb      = (ushort_t*)(ws);
  ushort_t* wqb     = (ushort_t*)(ws + ((size_t)8  << 20));
  ushort_t* wpb     = (ushort_t*)(ws + ((size_t)14 << 20));
  ushort_t* q_ws    = (ushort_t*)(ws + ((size_t)16 << 20));
  ushort_t* k_ws    = (ushort_t*)(ws + ((size_t)24 << 20));
  ushort_t* vT_ws   = (ushort_t*)(ws + ((size_t)32 << 20));
  ushort_t* attn_ws = (ushort_t*)(ws + ((size_t)40 << 20));

  cvt3_kernel<<<8192, 256, 0, stream>>>(x, w_qkv, w_proj, xb, wqb, wpb);

  gemm_qkv<<<32 * 24, 256, 0, stream>>>(xb, wqb, present, q_ws, k_ws, vT_ws);

  attn_kernel<<<512, 256, 0, stream>>>(q_ws, k_ws, vT_ws, attn_ws, cs);

  gemm_proj<<<32 * 16, 256, 0, stream>>>(attn_ws, wpb, out, b_proj);
}